// Round 8
// baseline (1769.626 us; speedup 1.0000x reference)
//
#include <hip/hip_runtime.h>
#include <math.h>

#define BB 32
#define NN 16384
#define GG 128
#define KK 64
#define HH 128
#define DD 384
#define LN_EPS 1e-5f
#define CAP 640
#define NTASK (BB * GG)

// round-to-nearest sum of 3 squares, matching jnp.sum(x**2, -1) order, no FMA contraction
__device__ __forceinline__ float sq3(float x, float y, float z) {
    return __fadd_rn(__fadd_rn(__fmul_rn(x, x), __fmul_rn(y, y)), __fmul_rn(z, z));
}

// order-preserving uint key of dist2, same formula/rounding as reference
__device__ __forceinline__ unsigned distkey(float px, float py, float pz, float4 c4) {
    float p2 = sq3(px, py, pz);
    float dot = __fadd_rn(__fadd_rn(__fmul_rn(c4.x, px), __fmul_rn(c4.y, py)),
                          __fmul_rn(c4.z, pz));
    float d = __fsub_rn(__fadd_rn(c4.w, p2), __fmul_rn(2.0f, dot));
    unsigned u = __float_as_uint(d);
    return u ^ ((u & 0x80000000u) ? 0xFFFFFFFFu : 0x80000000u);
}

// rank of this lane among set bits below it in a 64-bit wave mask
__device__ __forceinline__ unsigned lanerank(unsigned long long m) {
    unsigned r = __builtin_amdgcn_mbcnt_lo((unsigned)m, 0);
    return __builtin_amdgcn_mbcnt_hi((unsigned)(m >> 32), r);
}

// ---------------- prep: transpose w2 + zero the task/done sync area ----------------
__global__ void prep_kernel(const float* __restrict__ w2, float* __restrict__ w2t,
                            unsigned* __restrict__ syncArea) {
    int i = blockIdx.x * 256 + threadIdx.x;  // 192 blocks x 256 = 49152
    if (i < HH * DD) {
        int f = i >> 7, k = i & 127;
        w2t[i] = w2[k * DD + f];
    }
    if (i < NTASK + 64) syncArea[i] = 0u;  // done[4096] + taskCtr + pad
}

// per-wave group-phase scratch (16 waves) -- unioned with fps dist array.
struct GrpSh {
    unsigned candKey[16][CAP];        // 40 KB
    unsigned short candIdx[16][CAP];  // 20 KB
    unsigned short tieIdx[16][128];   // 4 KB
    unsigned short selIdx[16][KK];    // 2 KB
    float4 localPt[16][KK];           // 16 KB
    float hbar[16][HH];               // 8 KB
};                                    // 90 KB
struct FpsSh {
    float4 ds4[NN / 4];               // 64 KB
};
union ShU {
    FpsSh f;
    GrpSh g;
};

// Fused producer/consumer: blocks 0..31 run FPS for batch blockIdx (full CU each --
// LDS ~93KB forces 1 block/CU so producers never share a CU), publishing each
// centroid INDEX as the value of a relaxed agent-scope atomic (payload-in-word:
// no release fence needed; consumers recompute c4 from p[idx] bit-exactly).
// All blocks then pull group tasks (g-major round-robin, matching availability
// order) from a global queue. Consumers poll; producers never wait -> deadlock-free.
__global__ __launch_bounds__(1024) void fused_kernel(
    const float* __restrict__ pts, const float* __restrict__ w1,
    const float* __restrict__ b1, const float* __restrict__ w2t,
    const float* __restrict__ b2, const float* __restrict__ lns,
    const float* __restrict__ lnb, float* __restrict__ cent_out,
    float* __restrict__ tok_out, unsigned* __restrict__ done,
    unsigned* __restrict__ taskCtr) {
    __shared__ ShU sh;
    __shared__ unsigned long long slot[GG];
    const int tid = threadIdx.x, lane = tid & 63, wid = tid >> 6;

    if (blockIdx.x < BB) {
        // ================= producer: FPS (R7 structure, unchanged math) =========
        const int b = blockIdx.x;
        const float* p = pts + (size_t)b * NN * 3;
        const float4* p4 = (const float4*)p;
        for (int i = tid; i < NN / 4; i += 1024)
            sh.f.ds4[i] = make_float4(INFINITY, INFINITY, INFINITY, INFINITY);
        for (int i = tid; i < GG; i += 1024) slot[i] = 0ull;
        __syncthreads();

        float cx = p[0], cy = p[1], cz = p[2];  // deterministic start at index 0
        int curIdx = 0;
        for (int it = 0; it < GG; it++) {
            if (tid == 0) {
                float* co = cent_out + ((size_t)b * GG + it) * 3;
                co[0] = cx; co[1] = cy; co[2] = cz;
                __hip_atomic_store(&done[b * GG + it], (unsigned)(curIdx + 1),
                                   __ATOMIC_RELAXED, __HIP_MEMORY_SCOPE_AGENT);
            }
            if (it == GG - 1) break;  // last argmax unused

            float bv0 = -INFINITY, bv1 = -INFINITY, bv2 = -INFINITY, bv3 = -INFINITY;
            int bq0 = 0, bq1 = 0, bq2 = 0, bq3 = 0;
#pragma unroll
            for (int j = 0; j < 4; j++) {
                int q = tid + j * 1024;
                float4 A = p4[3 * q], B = p4[3 * q + 1], C = p4[3 * q + 2];
                float4 dv = sh.f.ds4[q];
                float d0 = sq3(__fsub_rn(A.x, cx), __fsub_rn(A.y, cy), __fsub_rn(A.z, cz));
                float d1 = sq3(__fsub_rn(A.w, cx), __fsub_rn(B.x, cy), __fsub_rn(B.y, cz));
                float d2 = sq3(__fsub_rn(B.z, cx), __fsub_rn(B.w, cy), __fsub_rn(C.x, cz));
                float d3 = sq3(__fsub_rn(C.y, cx), __fsub_rn(C.z, cy), __fsub_rn(C.w, cz));
                float n0 = fminf(dv.x, d0), n1 = fminf(dv.y, d1);
                float n2 = fminf(dv.z, d2), n3 = fminf(dv.w, d3);
                bool ch = (d0 < dv.x) | (d1 < dv.y) | (d2 < dv.z) | (d3 < dv.w);
                if (ch) sh.f.ds4[q] = make_float4(n0, n1, n2, n3);
                if (n0 > bv0) { bv0 = n0; bq0 = q; }
                if (n1 > bv1) { bv1 = n1; bq1 = q; }
                if (n2 > bv2) { bv2 = n2; bq2 = q; }
                if (n3 > bv3) { bv3 = n3; bq3 = q; }
            }
            float fv = bv0; int fi = 4 * bq0;
            {
                int i1 = 4 * bq1 + 1, i2 = 4 * bq2 + 2, i3 = 4 * bq3 + 3;
                if (bv1 > fv || (bv1 == fv && i1 < fi)) { fv = bv1; fi = i1; }
                if (bv2 > fv || (bv2 == fv && i2 < fi)) { fv = bv2; fi = i2; }
                if (bv3 > fv || (bv3 == fv && i3 < fi)) { fv = bv3; fi = i3; }
            }
#pragma unroll
            for (int off = 32; off >= 1; off >>= 1) {
                float ov = __shfl_down(fv, off);
                int oi = __shfl_down(fi, off);
                if (ov > fv || (ov == fv && oi < fi)) { fv = ov; fi = oi; }
            }
            // dist >= 0: float bits order-monotone; ~idx -> lowest index wins
            if ((tid & 63) == 0) {
                unsigned long long packed =
                    ((unsigned long long)__float_as_uint(fv) << 32) |
                    (unsigned)(0xFFFFFFFFu - (unsigned)fi);
                atomicMax(&slot[it], packed);
            }
            __syncthreads();  // only barrier per iteration
            unsigned long long w = slot[it];
            curIdx = (int)(0xFFFFFFFFu - (unsigned)w);
            const float* wp = p + (size_t)curIdx * 3;  // broadcast L1/L2-hit read
            cx = wp[0]; cy = wp[1]; cz = wp[2];
        }
    }
    __syncthreads();  // producer blocks: fps LDS dead, safe to reuse as GrpSh

    // ================= consumer loop (all 256 blocks; wave-per-group) ============
    for (;;) {
        unsigned t;
        if (lane == 0)
            t = __hip_atomic_fetch_add(taskCtr, 1u, __ATOMIC_RELAXED,
                                       __HIP_MEMORY_SCOPE_AGENT);
        t = (unsigned)__shfl((int)t, 0);
        if (t >= NTASK) break;
        const int b = (int)(t & 31u);   // g-major round-robin over batches
        const int g = (int)(t >> 5);

        // wait until fps(b) has produced centroid g; payload word = idx+1
        unsigned v;
        do {
            v = __hip_atomic_load(&done[b * GG + g], __ATOMIC_RELAXED,
                                  __HIP_MEMORY_SCOPE_AGENT);
            if (v) break;
            __builtin_amdgcn_s_sleep(4);
        } while (true);

        const float* p = pts + (size_t)b * NN * 3;
        const float4* p4 = (const float4*)p;
        const int cidx = (int)v - 1;
        float ccx = p[3 * cidx], ccy = p[3 * cidx + 1], ccz = p[3 * cidx + 2];
        float4 c4 = make_float4(ccx, ccy, ccz, sq3(ccx, ccy, ccz));  // == producer's

        // ---- sampling: 512 samples/wave (8/lane, stride 32 points)
        unsigned sk[8];
#pragma unroll
        for (int s = 0; s < 8; s++) {
            int n = (s * 64 + lane) * 32;
            sk[s] = distkey(p[n * 3], p[n * 3 + 1], p[n * 3 + 2], c4);
        }
        auto sample_kth = [&](int rank) -> unsigned {  // exact kth smallest of 512
            unsigned T = 0u;
            for (int bit = 31; bit >= 0; bit--) {
                unsigned c = T | (1u << bit);
                int cnt2 = 0;
#pragma unroll
                for (int s = 0; s < 8; s++) cnt2 += __popcll(__ballot(sk[s] < c));
                if (cnt2 < rank) T = c;
            }
            return T;
        };
        unsigned* ck = sh.g.candKey[wid];
        unsigned short* ci = sh.g.candIdx[wid];
        auto collect = [&](unsigned T) -> int {  // barrier-free wave-append
            int base = 0;
            for (int it2 = 0; it2 < 64; it2++) {
                int q = it2 * 64 + lane;
                float4 A = p4[3 * q], Bv = p4[3 * q + 1], Cv = p4[3 * q + 2];
                unsigned kk[4];
                kk[0] = distkey(A.x, A.y, A.z, c4);
                kk[1] = distkey(A.w, Bv.x, Bv.y, c4);
                kk[2] = distkey(Bv.z, Bv.w, Cv.x, c4);
                kk[3] = distkey(Cv.y, Cv.z, Cv.w, c4);
#pragma unroll
                for (int qq = 0; qq < 4; qq++) {
                    bool pred = kk[qq] <= T;
                    unsigned long long m = __ballot(pred);
                    if (pred) {
                        int pos = base + (int)lanerank(m);
                        if (pos < CAP) {
                            ck[pos] = kk[qq];
                            ci[pos] = (unsigned short)(4 * q + qq);
                        }
                    }
                    base += __popcll(m);
                }
            }
            return base;
        };

        int cnt = collect(sample_kth(8));                 // E[cnt] ~ 256
        if (cnt > CAP) cnt = collect(sample_kth(4));      // E[cnt] ~ 128, P ~ 0

        bool fallback = (cnt < KK || cnt > CAP);
        if (!fallback) {
            // ---- exact: 32-step ballot search for the 64th smallest KEY
            unsigned k8[10];
#pragma unroll
            for (int r = 0; r < 10; r++) {
                int s = r * 64 + lane;
                k8[r] = (s < cnt) ? ck[s] : 0xFFFFFFFFu;
            }
            unsigned T = 0u;
            for (int bit = 31; bit >= 0; bit--) {
                unsigned c = T | (1u << bit);
                int cl = 0;
#pragma unroll
                for (int r = 0; r < 10; r++) cl += __popcll(__ballot(k8[r] < c));
                if (cl < KK) T = c;  // final T = 64th smallest key
            }
            int cless = 0;
#pragma unroll
            for (int r = 0; r < 10; r++) cless += __popcll(__ballot(k8[r] < T));
            int need = KK - cless;
            int base2 = 0;
#pragma unroll
            for (int r = 0; r < 10; r++) {  // keys < T: in the set unconditionally
                bool pr = k8[r] < T;
                unsigned long long m = __ballot(pr);
                if (pr) sh.g.selIdx[wid][base2 + lanerank(m)] = ci[r * 64 + lane];
                base2 += __popcll(m);
            }
            int tb = 0;
#pragma unroll
            for (int r = 0; r < 10; r++) {  // ties at T: lowest `need` indices win
                bool pr = (r * 64 + lane < cnt) && (k8[r] == T);
                unsigned long long m = __ballot(pr);
                if (pr) {
                    int pos = tb + (int)lanerank(m);
                    if (pos < 128) sh.g.tieIdx[wid][pos] = ci[r * 64 + lane];
                }
                tb += __popcll(m);
            }
            if (tb > 128) {
                fallback = true;
            } else {
#pragma unroll
                for (int rr = 0; rr < 2; rr++) {
                    int tt = lane + rr * 64;
                    if (tt < tb) {
                        unsigned short my = sh.g.tieIdx[wid][tt];
                        int rank = 0;
                        for (int j2 = 0; j2 < tb; j2++)
                            rank += (sh.g.tieIdx[wid][j2] < my);
                        if (rank < need) sh.g.selIdx[wid][cless + rank] = my;
                    }
                }
            }
        }
        if (fallback) {
            // exact 64-round min-extraction with recompute (p ~ 0; barrier-free)
            unsigned long long last = 0ull;
            for (int r = 0; r < KK; r++) {
                unsigned long long best = ~0ull;
                for (int it2 = 0; it2 < 64; it2++) {
                    int q = it2 * 64 + lane;
                    float4 A = p4[3 * q], Bv = p4[3 * q + 1], Cv = p4[3 * q + 2];
                    unsigned kk[4];
                    kk[0] = distkey(A.x, A.y, A.z, c4);
                    kk[1] = distkey(A.w, Bv.x, Bv.y, c4);
                    kk[2] = distkey(Bv.z, Bv.w, Cv.x, c4);
                    kk[3] = distkey(Cv.y, Cv.z, Cv.w, c4);
#pragma unroll
                    for (int qq = 0; qq < 4; qq++) {
                        unsigned long long pp =
                            (((unsigned long long)kk[qq]) << 16) | (unsigned)(4 * q + qq);
                        if ((r == 0 || pp > last) && pp < best) best = pp;
                    }
                }
#pragma unroll
                for (int off = 32; off >= 1; off >>= 1) {
                    unsigned long long o = __shfl_xor(best, off);
                    if (o < best) best = o;
                }
                sh.g.selIdx[wid][r] = (unsigned short)(best & 0xFFFFu);
                last = best;
            }
        }

        // ---- gather local coords (wave-internal)
        {
            int n = sh.g.selIdx[wid][lane];
            sh.g.localPt[wid][lane] = make_float4(p[n * 3] - c4.x, p[n * 3 + 1] - c4.y,
                                                  p[n * 3 + 2] - c4.z, 0.f);
        }
        // ---- layer1 + exact GELU + mean over 64 neighbors (2 features per lane)
        {
            float wa0 = w1[lane], wb0 = w1[HH + lane], wc0 = w1[2 * HH + lane],
                  bb0 = b1[lane];
            float wa1 = w1[64 + lane], wb1 = w1[HH + 64 + lane],
                  wc1 = w1[2 * HH + 64 + lane], bb1 = b1[64 + lane];
            float s0 = 0.f, s1 = 0.f;
            for (int k = 0; k < KK; k++) {
                float4 lp = sh.g.localPt[wid][k];  // broadcast LDS read
                float a0 = lp.x * wa0 + lp.y * wb0 + lp.z * wc0 + bb0;
                float a1 = lp.x * wa1 + lp.y * wb1 + lp.z * wc1 + bb1;
                s0 += 0.5f * a0 * (1.0f + erff(a0 * 0.70710678118654752440f));
                s1 += 0.5f * a1 * (1.0f + erff(a1 * 0.70710678118654752440f));
            }
            sh.g.hbar[wid][lane] = s0 * (1.0f / 64.0f);
            sh.g.hbar[wid][64 + lane] = s1 * (1.0f / 64.0f);
        }
        // ---- layer2 (mean commutes with linear): 6 features per lane, then LN
        {
            const int f0 = lane * 6;
            float acc0 = b2[f0], acc1 = b2[f0 + 1], acc2 = b2[f0 + 2];
            float acc3 = b2[f0 + 3], acc4 = b2[f0 + 4], acc5 = b2[f0 + 5];
            const float4* hb = (const float4*)sh.g.hbar[wid];
            for (int q = 0; q < HH / 4; q++) {
                float4 h4 = hb[q];  // broadcast
                const float* w0 = w2t + (size_t)f0 * HH + 4 * q;
                float4 a = *(const float4*)(w0);
                float4 bq = *(const float4*)(w0 + HH);
                float4 cq = *(const float4*)(w0 + 2 * HH);
                float4 dq = *(const float4*)(w0 + 3 * HH);
                float4 eq = *(const float4*)(w0 + 4 * HH);
                float4 fq = *(const float4*)(w0 + 5 * HH);
                acc0 += h4.x * a.x + h4.y * a.y + h4.z * a.z + h4.w * a.w;
                acc1 += h4.x * bq.x + h4.y * bq.y + h4.z * bq.z + h4.w * bq.w;
                acc2 += h4.x * cq.x + h4.y * cq.y + h4.z * cq.z + h4.w * cq.w;
                acc3 += h4.x * dq.x + h4.y * dq.y + h4.z * dq.z + h4.w * dq.w;
                acc4 += h4.x * eq.x + h4.y * eq.y + h4.z * eq.z + h4.w * eq.w;
                acc5 += h4.x * fq.x + h4.y * fq.y + h4.z * fq.z + h4.w * fq.w;
            }
            float s1v = acc0 + acc1 + acc2 + acc3 + acc4 + acc5;
            float s2v = acc0 * acc0 + acc1 * acc1 + acc2 * acc2 + acc3 * acc3 +
                        acc4 * acc4 + acc5 * acc5;
#pragma unroll
            for (int off = 32; off >= 1; off >>= 1) {
                s1v += __shfl_xor(s1v, off);
                s2v += __shfl_xor(s2v, off);
            }
            float mu = s1v / (float)DD;
            float var = s2v / (float)DD - mu * mu;
            float rstd = rsqrtf(var + LN_EPS);
            float* outp = tok_out + ((size_t)b * GG + g) * DD + f0;
            outp[0] = (acc0 - mu) * rstd * lns[f0] + lnb[f0];
            outp[1] = (acc1 - mu) * rstd * lns[f0 + 1] + lnb[f0 + 1];
            outp[2] = (acc2 - mu) * rstd * lns[f0 + 2] + lnb[f0 + 2];
            outp[3] = (acc3 - mu) * rstd * lns[f0 + 3] + lnb[f0 + 3];
            outp[4] = (acc4 - mu) * rstd * lns[f0 + 4] + lnb[f0 + 4];
            outp[5] = (acc5 - mu) * rstd * lns[f0 + 5] + lnb[f0 + 5];
        }
    }
}

extern "C" void kernel_launch(void* const* d_in, const int* in_sizes, int n_in,
                              void* d_out, int out_size, void* d_ws, size_t ws_size,
                              hipStream_t stream) {
    const float* pts = (const float*)d_in[0];
    const float* w1 = (const float*)d_in[1];
    const float* b1 = (const float*)d_in[2];
    const float* w2 = (const float*)d_in[3];
    const float* b2 = (const float*)d_in[4];
    const float* lns = (const float*)d_in[5];
    const float* lnb = (const float*)d_in[6];
    float* out = (float*)d_out;

    // ws layout: w2t 192KB @0 | done[4096]+taskCtr @192KB
    float* w2t = (float*)d_ws;
    unsigned* syncArea = (unsigned*)((char*)d_ws + 196608);
    unsigned* done = syncArea;
    unsigned* taskCtr = syncArea + NTASK;

    prep_kernel<<<192, 256, 0, stream>>>(w2, w2t, syncArea);
    fused_kernel<<<256, 1024, 0, stream>>>(pts, w1, b1, w2t, b2, lns, lnb,
                                           out, out + BB * GG * 3, done, taskCtr);
}